// Round 1
// baseline (244.131 us; speedup 1.0000x reference)
//
#include <hip/hip_runtime.h>
#include <stdint.h>

#define CUBE_LEN   512
#define EQU_H      1024
#define EQU_W      2048
#define EQU_COUNT  4
#define CHANNELS   3

// One thread per equirect pixel (h,w). Bilinear taps re-parameterized:
//   x0 = clamp(floor(u), 0, 510), wx = u - x0  (wx==1 when u==511)
// so x1 = x0+1, y1 = y0+1 always -> the 4 taps of each (e,c) image live at
// byte offsets {0, 4, 2048, 2052} from the o00 address: ALL four fit in the
// 13-bit signed immediate offset of global_load_dword.
//
// Round-7: counters proved round-6's hoist never happened (VGPR=40 < 48
// results). Compiler chunks the gathers with interleaved waitcnts -> ~6
// serialized memory round trips per wave -> latency-bound at 1.6 TB/s.
// Fix: issue all 48 gathers as inline-asm global_load_dword (saddr = SGPR
// base, 32-bit voffset per (e,c), imm offset per tap), then ONE manual
// s_waitcnt vmcnt(0). sched_barrier(0) after the waitcnt is mandatory:
// hipcc otherwise hoists register-only FMAs past an inline-asm waitcnt.
__global__ __launch_bounds__(256, 1) void cube2equirec_kernel(
    const float* __restrict__ x,
    const float* __restrict__ uv,
    const int*   __restrict__ face,
    float*       __restrict__ out)
{
    const int HW  = EQU_H * EQU_W;          // 1 << 21
    const int idx = blockIdx.x * blockDim.x + threadIdx.x;
    if (idx >= HW) return;

    const float2 uvv = ((const float2*)uv)[idx];
    const float u = uvv.x;
    const float v = uvv.y;
    const int   f = face[idx];

    int x0 = (int)floorf(u);
    int y0 = (int)floorf(v);
    x0 = min(max(x0, 0), CUBE_LEN - 2);     // 0..510
    y0 = min(max(y0, 0), CUBE_LEN - 2);

    const float wx = u - (float)x0;         // in [0,1]
    const float wy = v - (float)y0;

    const int o00   = y0 * CUBE_LEN + x0;   // (y0, x0)
    const int PLANE = CUBE_LEN * CUBE_LEN;  // 262144
    const int IMG   = CHANNELS * PLANE;     // 786432

    // Scalar 64-bit base for saddr-form global_load.
    const uint64_t xbase = (uint64_t)x;

    // 12 per-lane byte offsets (one per (e,c) image at tap00).
    // Max = ((23*786432) + 2*262144 + 262143)*4 = 75.5 MB < 2^31. Fits u32.
    uint32_t voff[EQU_COUNT * CHANNELS];
#pragma unroll
    for (int e = 0; e < EQU_COUNT; ++e) {
        const int img_base = (e * 6 + f) * IMG;
#pragma unroll
        for (int c = 0; c < CHANNELS; ++c) {
            voff[e * CHANNELS + c] =
                (uint32_t)((img_base + c * PLANE + o00) * 4);
        }
    }

    // ---- 48 gathers, all issued before any wait ----
    float r00[EQU_COUNT * CHANNELS], r01[EQU_COUNT * CHANNELS];
    float r10[EQU_COUNT * CHANNELS], r11[EQU_COUNT * CHANNELS];
#pragma unroll
    for (int i = 0; i < EQU_COUNT * CHANNELS; ++i) {
        asm volatile(
            "global_load_dword %0, %4, %5\n\t"
            "global_load_dword %1, %4, %5 offset:4\n\t"
            "global_load_dword %2, %4, %5 offset:2048\n\t"
            "global_load_dword %3, %4, %5 offset:2052"
            : "=&v"(r00[i]), "=&v"(r01[i]), "=&v"(r10[i]), "=&v"(r11[i])
            : "v"(voff[i]), "s"(xbase));
    }

    // Single drain for all 48 loads; fence the compiler scheduler so no
    // consumer is hoisted above the wait (rule #18).
    asm volatile("s_waitcnt vmcnt(0)" ::: "memory");
    __builtin_amdgcn_sched_barrier(0);

    // ---- compute + store ----
    const float w00 = (1.0f - wx) * (1.0f - wy);
    const float w01 = wx * (1.0f - wy);
    const float w10 = (1.0f - wx) * wy;
    const float w11 = wx * wy;

#pragma unroll
    for (int i = 0; i < EQU_COUNT * CHANNELS; ++i) {
        const float val = r00[i] * w00 + r01[i] * w01
                        + r10[i] * w10 + r11[i] * w11;
        __builtin_nontemporal_store(val, &out[i * HW + idx]);
    }
}

extern "C" void kernel_launch(void* const* d_in, const int* in_sizes, int n_in,
                              void* d_out, int out_size, void* d_ws, size_t ws_size,
                              hipStream_t stream) {
    const float* x    = (const float*)d_in[0];
    const float* uv   = (const float*)d_in[1];
    const int*   face = (const int*)d_in[2];
    float*       out  = (float*)d_out;

    const int HW = EQU_H * EQU_W;
    const int block = 256;
    const int grid  = (HW + block - 1) / block;  // 8192 blocks

    hipLaunchKernelGGL(cube2equirec_kernel, dim3(grid), dim3(block), 0, stream,
                       x, uv, face, out);
}

// Round 2
// 214.412 us; speedup vs baseline: 1.1386x; 1.1386x over previous
//
#include <hip/hip_runtime.h>
#include <stdint.h>

#define CUBE_LEN   512
#define EQU_H      1024
#define EQU_W      2048
#define EQU_COUNT  4
#define CHANNELS   3

typedef float f32x2 __attribute__((ext_vector_type(2)));

// One thread per equirect pixel. Bilinear taps re-parameterized so
// x1 = x0+1, y1 = y0+1 always: the 4 taps of each (e,c) image are two
// ADJACENT float pairs, rows 2048 bytes apart -> 2x global_load_dwordx2
// with imm offset 0 / 2048 per image.
//
// Round-8: round-7's per-iteration asm with ARRAY outputs was demoted to
// scratch (VGPR=28 < 48 results; scratch stores force per-load vmcnt(0)
// => 48 serialized round trips, 120us). Fix: named scalar outputs (pure
// SSA -> guaranteed VGPRs) and ONE asm block holding all 24 loads + the
// single s_waitcnt, so no consumer can be scheduled into the window.
// Uniform (e,c) image offsets are folded into SGPR bases (scalar adds);
// only one per-lane voffset VGPR.
__global__ __launch_bounds__(256, 1) void cube2equirec_kernel(
    const float* __restrict__ x,
    const float* __restrict__ uv,
    const int*   __restrict__ face,
    float*       __restrict__ out)
{
    const int HW  = EQU_H * EQU_W;          // 1 << 21
    const int idx = blockIdx.x * blockDim.x + threadIdx.x;
    if (idx >= HW) return;

    const float2 uvv = ((const float2*)uv)[idx];
    const float u = uvv.x;
    const float v = uvv.y;
    const int   f = face[idx];

    int x0 = (int)floorf(u);
    int y0 = (int)floorf(v);
    x0 = min(max(x0, 0), CUBE_LEN - 2);     // 0..510
    y0 = min(max(y0, 0), CUBE_LEN - 2);

    const float wx = u - (float)x0;         // in [0,1]
    const float wy = v - (float)y0;

    // per-lane byte offset inside the face-f block: face + row + col
    const uint32_t vb = (uint32_t)(f * 3145728 + y0 * (CUBE_LEN * 4) + x0 * 4);
    const uint64_t xb = (uint64_t)x;

    // uniform (e,c) byte offsets -> SGPR bases (3145728 B per face-image,
    // 18874368 B per equirect set, 1048576 B per channel plane)
#define ECB(e, c) ((uint64_t)((e) * 18874368u + (c) * 1048576u))

    // 12 images x {row0 pair, row1 pair}; all named scalars (SSA -> VGPRs)
    f32x2 ta0, tb0, ta1, tb1, ta2,  tb2,  ta3,  tb3,
          ta4, tb4, ta5, tb5, ta6,  tb6,  ta7,  tb7,
          ta8, tb8, ta9, tb9, ta10, tb10, ta11, tb11;

    asm volatile(
        "global_load_dwordx2 %[a0],  %[vb], %[s0]\n\t"
        "global_load_dwordx2 %[b0],  %[vb], %[s0] offset:2048\n\t"
        "global_load_dwordx2 %[a1],  %[vb], %[s1]\n\t"
        "global_load_dwordx2 %[b1],  %[vb], %[s1] offset:2048\n\t"
        "global_load_dwordx2 %[a2],  %[vb], %[s2]\n\t"
        "global_load_dwordx2 %[b2],  %[vb], %[s2] offset:2048\n\t"
        "global_load_dwordx2 %[a3],  %[vb], %[s3]\n\t"
        "global_load_dwordx2 %[b3],  %[vb], %[s3] offset:2048\n\t"
        "global_load_dwordx2 %[a4],  %[vb], %[s4]\n\t"
        "global_load_dwordx2 %[b4],  %[vb], %[s4] offset:2048\n\t"
        "global_load_dwordx2 %[a5],  %[vb], %[s5]\n\t"
        "global_load_dwordx2 %[b5],  %[vb], %[s5] offset:2048\n\t"
        "global_load_dwordx2 %[a6],  %[vb], %[s6]\n\t"
        "global_load_dwordx2 %[b6],  %[vb], %[s6] offset:2048\n\t"
        "global_load_dwordx2 %[a7],  %[vb], %[s7]\n\t"
        "global_load_dwordx2 %[b7],  %[vb], %[s7] offset:2048\n\t"
        "global_load_dwordx2 %[a8],  %[vb], %[s8]\n\t"
        "global_load_dwordx2 %[b8],  %[vb], %[s8] offset:2048\n\t"
        "global_load_dwordx2 %[a9],  %[vb], %[s9]\n\t"
        "global_load_dwordx2 %[b9],  %[vb], %[s9] offset:2048\n\t"
        "global_load_dwordx2 %[a10], %[vb], %[s10]\n\t"
        "global_load_dwordx2 %[b10], %[vb], %[s10] offset:2048\n\t"
        "global_load_dwordx2 %[a11], %[vb], %[s11]\n\t"
        "global_load_dwordx2 %[b11], %[vb], %[s11] offset:2048\n\t"
        "s_waitcnt vmcnt(0)"
        : [a0] "=&v"(ta0),  [b0] "=&v"(tb0),
          [a1] "=&v"(ta1),  [b1] "=&v"(tb1),
          [a2] "=&v"(ta2),  [b2] "=&v"(tb2),
          [a3] "=&v"(ta3),  [b3] "=&v"(tb3),
          [a4] "=&v"(ta4),  [b4] "=&v"(tb4),
          [a5] "=&v"(ta5),  [b5] "=&v"(tb5),
          [a6] "=&v"(ta6),  [b6] "=&v"(tb6),
          [a7] "=&v"(ta7),  [b7] "=&v"(tb7),
          [a8] "=&v"(ta8),  [b8] "=&v"(tb8),
          [a9] "=&v"(ta9),  [b9] "=&v"(tb9),
          [a10] "=&v"(ta10), [b10] "=&v"(tb10),
          [a11] "=&v"(ta11), [b11] "=&v"(tb11)
        : [vb] "v"(vb),
          [s0]  "s"(xb + ECB(0, 0)), [s1]  "s"(xb + ECB(0, 1)),
          [s2]  "s"(xb + ECB(0, 2)), [s3]  "s"(xb + ECB(1, 0)),
          [s4]  "s"(xb + ECB(1, 1)), [s5]  "s"(xb + ECB(1, 2)),
          [s6]  "s"(xb + ECB(2, 0)), [s7]  "s"(xb + ECB(2, 1)),
          [s8]  "s"(xb + ECB(2, 2)), [s9]  "s"(xb + ECB(3, 0)),
          [s10] "s"(xb + ECB(3, 1)), [s11] "s"(xb + ECB(3, 2)));

    // ---- compute + store (results already waited inside the asm) ----
    const float w00 = (1.0f - wx) * (1.0f - wy);
    const float w01 = wx * (1.0f - wy);
    const float w10 = (1.0f - wx) * wy;
    const float w11 = wx * wy;

#define EMIT(i, A, B)                                                        \
    {                                                                        \
        const float val = A.x * w00 + A.y * w01 + B.x * w10 + B.y * w11;     \
        __builtin_nontemporal_store(val, &out[(i) * HW + idx]);              \
    }

    EMIT(0,  ta0,  tb0)
    EMIT(1,  ta1,  tb1)
    EMIT(2,  ta2,  tb2)
    EMIT(3,  ta3,  tb3)
    EMIT(4,  ta4,  tb4)
    EMIT(5,  ta5,  tb5)
    EMIT(6,  ta6,  tb6)
    EMIT(7,  ta7,  tb7)
    EMIT(8,  ta8,  tb8)
    EMIT(9,  ta9,  tb9)
    EMIT(10, ta10, tb10)
    EMIT(11, ta11, tb11)
}

extern "C" void kernel_launch(void* const* d_in, const int* in_sizes, int n_in,
                              void* d_out, int out_size, void* d_ws, size_t ws_size,
                              hipStream_t stream) {
    const float* x    = (const float*)d_in[0];
    const float* uv   = (const float*)d_in[1];
    const int*   face = (const int*)d_in[2];
    float*       out  = (float*)d_out;

    const int HW = EQU_H * EQU_W;
    const int block = 256;
    const int grid  = (HW + block - 1) / block;  // 8192 blocks

    hipLaunchKernelGGL(cube2equirec_kernel, dim3(grid), dim3(block), 0, stream,
                       x, uv, face, out);
}